// Round 7
// baseline (928.848 us; speedup 1.0000x reference)
//
#include <hip/hip_runtime.h>
#include <math.h>

// Round 7: REVERT to round-4 structure (validated passing, absmax 3.9e-3),
// fixing its two measured regressions:
//  - LDS 54784 B was 171 B over the 3-blocks/CU line (54613) -> 2 blocks/CU.
//    Fix: drop gelu LUT (1 KB) + x pitch 264->260 => ~52.8 KB -> 3 blocks/CU.
//  - gelu LDS LUT (3.2e7 bank conflicts, dependent gathers) -> A&S polynomial.
// The round-5/6 K-split is ABANDONED: fp16 vs bf16 barely changed its ~2e-2
// error (2.05e-2 -> 1.95e-2), proving a dtype-independent structural defect
// in the K-split, not quantization noise.
// Chain dtype = fp16 (same MFMA rate as bf16, 8x smaller quantization error
// -> margin instead of round-2..4's 1-ulp pass).
#define KN 32
#define DD 128
#define FF 256
#define QB 2
#define MROWS 64
#define HP 136      // hln pitch (half): [64][136]
#define XP 260      // x pitch (half):   [64][260] = 33280 B (was 264; -512 B)
#define H2P 72      // h2^T pitch (half): [128][72] = 18432 B (aliases hln)
#define PLP 264     // pln pitch (half): [16][264]

typedef _Float16 f16x8 __attribute__((ext_vector_type(8)));
typedef float f32x4 __attribute__((ext_vector_type(4)));

__device__ __forceinline__ unsigned pk2h(float a, float b) {
    union { _Float16 h[2]; unsigned u; } c;
    c.h[0] = (_Float16)a; c.h[1] = (_Float16)b;
    return c.u;
}
// gelu via A&S 7.1.26 erf (|err|<=1.5e-7), pure VALU (validated round 3)
__device__ __forceinline__ float gelu_f(float x) {
    float z  = __builtin_fabsf(x) * 0.70710678118654752440f;
    float e  = __builtin_amdgcn_exp2f(z * z * -1.4426950408889634f);
    float t  = __builtin_amdgcn_rcpf(fmaf(0.3275911f, z, 1.0f));
    float p  = fmaf(1.061405429f, t, -1.453152027f);
    p = fmaf(p, t, 1.421413741f);
    p = fmaf(p, t, -0.284496736f);
    p = fmaf(p, t, 0.254829592f);
    p = p * t;
    float erfz = fmaf(-p, e, 1.0f);
    float erfs = (x < 0.0f) ? -erfz : erfz;
    float hx = 0.5f * x;
    return fmaf(hx, erfs, hx);
}

// Prep: w1 [256,128], w2 [128,256], hw1 [256,256] -> fp16 (natural layout).
__global__ void prep_kernel(const float* __restrict__ w1,
                            const float* __restrict__ w2,
                            const float* __restrict__ hw1,
                            _Float16* __restrict__ w1h,
                            _Float16* __restrict__ w2h,
                            _Float16* __restrict__ hw1h) {
    int i = blockIdx.x * 256 + threadIdx.x;   // 0..65535
    if (i < 32768) { w1h[i] = (_Float16)w1[i]; w2h[i] = (_Float16)w2[i]; }
    hw1h[i] = (_Float16)hw1[i];
}

__launch_bounds__(256, 3)
__global__ void ff_mfma_kernel(
    const float* __restrict__ xyt_q,
    const float* __restrict__ obs_coords,
    const float* __restrict__ obs_vals,
    const int*   __restrict__ nb_idx,
    const float* __restrict__ log_gammas,
    const float* __restrict__ w_in,   // [128,4]
    const float* __restrict__ b_in,
    const float* __restrict__ ln1_g,
    const float* __restrict__ ln1_b,
    const _Float16* __restrict__ w1h,  // [256,128] fp16
    const float* __restrict__ b1,
    const _Float16* __restrict__ w2h,  // [128,256] fp16
    const float* __restrict__ b2,
    const float* __restrict__ hln_g,
    const float* __restrict__ hln_b,
    const _Float16* __restrict__ hw1h, // [256,256] fp16
    const float* __restrict__ hb1,
    const float* __restrict__ hw2,
    const float* __restrict__ hb2,
    float* __restrict__ out)
{
    __shared__ __align__(16) _Float16 s_u[9216];          // 18432 B: hln[64][136] / h2T[128][72]
    __shared__ __align__(16) unsigned char s_big[33280];  // x[64][260] f16 / pool+pln+hd
    __shared__ __align__(16) float s_tokf[MROWS][4];
    __shared__ float s_mu[QB], s_sig[QB];
    __shared__ float s_red[4][QB];

    const int t    = threadIdx.x;
    const int lane = t & 63;
    const int wv   = t >> 6;
    const int m16  = lane & 15;
    const int quad = lane >> 4;
    const int q0   = blockIdx.x * QB;

    _Float16* s_hA   = s_u;                          // [64][HP]
    _Float16* h2T    = s_u;                          // [128][H2P]
    _Float16* s_x    = (_Float16*)s_big;             // [64][XP]
    float*    s_pool = (float*)s_big;                // [2][256] = 2048 B
    _Float16* s_pln  = (_Float16*)(s_big + 2048);    // [16][PLP] rows 2-15 garbage (finite)
    float*    s_hd   = (float*)(s_big + 10496);      // [2][256] = 2048 B

    // ---- Phase 0: gather, tokens, mu/sigma (ddof=1, clip 1e-3) ----
    if (t < MROWS) {
        int qi = t >> 5, j = t & 31;
        int q = q0 + qi;
        int idx = nb_idx[q * KN + j];
        float v = obs_vals[idx];
        float g0 = expf(log_gammas[0]), g1 = expf(log_gammas[1]), g2 = expf(log_gammas[2]);
        s_tokf[t][0] = (obs_coords[idx * 3 + 0] - xyt_q[q * 3 + 0]) * g0;
        s_tokf[t][1] = (obs_coords[idx * 3 + 1] - xyt_q[q * 3 + 1]) * g1;
        s_tokf[t][2] = (obs_coords[idx * 3 + 2] - xyt_q[q * 3 + 2]) * g2;
        float s = v, ss = v * v;
        #pragma unroll
        for (int m = 1; m < 32; m <<= 1) {
            s  += __shfl_xor(s, m);
            ss += __shfl_xor(ss, m);
        }
        float mu  = s * (1.0f / KN);
        float var = (ss - (float)KN * mu * mu) * (1.0f / (KN - 1));
        float sig = fmaxf(sqrtf(fmaxf(var, 0.0f)), 1e-3f);
        if (j == 0) { s_mu[qi] = mu; s_sig[qi] = sig; }
        s_tokf[t][3] = (v - mu) / sig;
    }
    __syncthreads();

    // ---- Phase 1: merged embed + LN; lane owns dims {2L,2L+1}, wave owns 16 tokens ----
    {
        const float4 wlo = ((const float4*)w_in)[2 * lane];
        const float4 whi = ((const float4*)w_in)[2 * lane + 1];
        const float2 bb  = *(const float2*)&b_in[2 * lane];
        const float2 gg  = *(const float2*)&ln1_g[2 * lane];
        const float2 cc  = *(const float2*)&ln1_b[2 * lane];
        #pragma unroll 4
        for (int i = 0; i < 16; i++) {
            int tok = wv * 16 + i;
            float4 tk = *(const float4*)&s_tokf[tok][0];
            float a0 = fmaf(wlo.x, tk.x, fmaf(wlo.y, tk.y, fmaf(wlo.z, tk.z, fmaf(wlo.w, tk.w, bb.x))));
            float a1 = fmaf(whi.x, tk.x, fmaf(whi.y, tk.y, fmaf(whi.z, tk.z, fmaf(whi.w, tk.w, bb.y))));
            float v0 = gelu_f(a0);
            float v1 = gelu_f(a1);
            float s = v0 + v1, ss = v0 * v0 + v1 * v1;
            #pragma unroll
            for (int m = 1; m < 64; m <<= 1) {
                s  += __shfl_xor(s, m);
                ss += __shfl_xor(ss, m);
            }
            float mean = s * (1.0f / DD);
            float var  = ss * (1.0f / DD) - mean * mean;
            float rstd = rsqrtf(fmaxf(var, 0.0f) + 1e-5f);
            float y0 = fmaf((v0 - mean) * rstd, gg.x, cc.x);
            float y1 = fmaf((v1 - mean) * rstd, gg.y, cc.y);
            *(unsigned*)&s_hA[tok * HP + 2 * lane] = pk2h(y0, y1);
        }
    }
    __syncthreads();

    // ---- Phase 3: MFMA GEMM1  x[tok][F] = gelu(hln @ w1^T + b1); wave strip F in [wv*64,+64) ----
    {
        f16x8 B[4][4];
        #pragma unroll
        for (int ct = 0; ct < 4; ct++)
            #pragma unroll
            for (int kk = 0; kk < 4; kk++)
                B[ct][kk] = *(const f16x8*)&w1h[(wv * 64 + ct * 16 + m16) * 128 + kk * 32 + quad * 8];
        #pragma unroll
        for (int rt = 0; rt < 4; rt++) {
            f16x8 A[4];
            #pragma unroll
            for (int kk = 0; kk < 4; kk++)
                A[kk] = *(const f16x8*)&s_hA[(rt * 16 + m16) * HP + kk * 32 + quad * 8];
            #pragma unroll
            for (int ct = 0; ct < 4; ct++) {
                f32x4 acc = {0.f, 0.f, 0.f, 0.f};
                #pragma unroll
                for (int kk = 0; kk < 4; kk++)
                    acc = __builtin_amdgcn_mfma_f32_16x16x32_f16(A[kk], B[ct][kk], acc, 0, 0, 0);
                int col = wv * 64 + ct * 16 + m16;
                float bb = b1[col];
                int r0 = rt * 16 + quad * 4;
                s_x[(r0 + 0) * XP + col] = (_Float16)gelu_f(acc[0] + bb);
                s_x[(r0 + 1) * XP + col] = (_Float16)gelu_f(acc[1] + bb);
                s_x[(r0 + 2) * XP + col] = (_Float16)gelu_f(acc[2] + bb);
                s_x[(r0 + 3) * XP + col] = (_Float16)gelu_f(acc[3] + bb);
            }
        }
    }
    __syncthreads();

    // ---- Phase 4 (swapped): h2T[d][tok] = gelu(w2 @ x^T + b2); A=w2 rows d, B=x rows tok ----
    {
        #pragma unroll
        for (int mt = 0; mt < 2; mt++) {
            int dbase = (wv * 2 + mt) * 16;
            f16x8 A2[8];
            #pragma unroll
            for (int kk = 0; kk < 8; kk++)
                A2[kk] = *(const f16x8*)&w2h[(dbase + m16) * 256 + kk * 32 + quad * 8];
            float bb0 = b2[dbase + quad * 4 + 0];
            float bb1 = b2[dbase + quad * 4 + 1];
            float bb2 = b2[dbase + quad * 4 + 2];
            float bb3 = b2[dbase + quad * 4 + 3];
            #pragma unroll
            for (int nt = 0; nt < 4; nt++) {
                f32x4 acc = {0.f, 0.f, 0.f, 0.f};
                #pragma unroll
                for (int kk = 0; kk < 8; kk++) {
                    f16x8 Bf = *(const f16x8*)&s_x[(nt * 16 + m16) * XP + kk * 32 + quad * 8];
                    acc = __builtin_amdgcn_mfma_f32_16x16x32_f16(A2[kk], Bf, acc, 0, 0, 0);
                }
                int tok = nt * 16 + m16;
                int d0 = dbase + quad * 4;
                h2T[(d0 + 0) * H2P + tok] = (_Float16)gelu_f(acc[0] + bb0);
                h2T[(d0 + 1) * H2P + tok] = (_Float16)gelu_f(acc[1] + bb1);
                h2T[(d0 + 2) * H2P + tok] = (_Float16)gelu_f(acc[2] + bb2);
                h2T[(d0 + 3) * H2P + tok] = (_Float16)gelu_f(acc[3] + bb3);
            }
        }
    }
    __syncthreads();

    // ---- Phase 5: pool mean/max over K=32 (contiguous 16B reads of h2T rows) ----
    {
        int d = t & 127, qi = t >> 7;
        const f16x8* rp = (const f16x8*)&h2T[d * H2P + qi * 32];
        float sm = 0.f, mx = -INFINITY;
        #pragma unroll
        for (int j = 0; j < 4; j++) {
            f16x8 v8 = rp[j];
            #pragma unroll
            for (int e = 0; e < 8; e++) {
                float v = (float)v8[e];
                sm += v; mx = fmaxf(mx, v);
            }
        }
        s_pool[qi * 256 + d]       = sm * (1.0f / KN);
        s_pool[qi * 256 + 128 + d] = mx;
    }
    __syncthreads();

    // ---- Phase 6: head LN over 256 -> fp16 s_pln rows 0..1 ----
    if (t < 128) {
        int qi = t >> 6, l = t & 63;
        float v0 = s_pool[qi * 256 + l],       v1 = s_pool[qi * 256 + l + 64];
        float v2 = s_pool[qi * 256 + l + 128], v3 = s_pool[qi * 256 + l + 192];
        float s = v0 + v1 + v2 + v3;
        float ss = v0 * v0 + v1 * v1 + v2 * v2 + v3 * v3;
        #pragma unroll
        for (int m = 1; m < 64; m <<= 1) {
            s  += __shfl_xor(s, m);
            ss += __shfl_xor(ss, m);
        }
        float mean = s * (1.0f / (2 * DD));
        float var  = ss * (1.0f / (2 * DD)) - mean * mean;
        float rstd = rsqrtf(fmaxf(var, 0.0f) + 1e-5f);
        s_pln[qi * PLP + l]       = (_Float16)((v0 - mean) * rstd * hln_g[l]       + hln_b[l]);
        s_pln[qi * PLP + l + 64]  = (_Float16)((v1 - mean) * rstd * hln_g[l + 64]  + hln_b[l + 64]);
        s_pln[qi * PLP + l + 128] = (_Float16)((v2 - mean) * rstd * hln_g[l + 128] + hln_b[l + 128]);
        s_pln[qi * PLP + l + 192] = (_Float16)((v3 - mean) * rstd * hln_g[l + 192] + hln_b[l + 192]);
    }
    __syncthreads();

    // ---- Phase 7a: head GEMM via MFMA; A rows 0/1 = queries (rows 2-15 garbage, unused) ----
    {
        f16x8 Ah[8];
        #pragma unroll
        for (int kk = 0; kk < 8; kk++)
            Ah[kk] = *(const f16x8*)&s_pln[m16 * PLP + kk * 32 + quad * 8];
        #pragma unroll
        for (int ct = 0; ct < 4; ct++) {
            int f = wv * 64 + ct * 16 + m16;
            f32x4 acc = {0.f, 0.f, 0.f, 0.f};
            #pragma unroll
            for (int kk = 0; kk < 8; kk++) {
                f16x8 Bf = *(const f16x8*)&hw1h[f * 256 + kk * 32 + quad * 8];
                acc = __builtin_amdgcn_mfma_f32_16x16x32_f16(Ah[kk], Bf, acc, 0, 0, 0);
            }
            if (quad == 0) {
                s_hd[f]       = acc[0];   // query 0
                s_hd[256 + f] = acc[1];   // query 1
            }
        }
    }
    __syncthreads();

    // ---- Phase 7b: gelu + dot(hw2) + reduce ----
    {
        float a0 = s_hd[t]       + hb1[t];
        float a1 = s_hd[256 + t] + hb1[t];
        float hv = hw2[t];
        float c0 = gelu_f(a0) * hv;
        float c1 = gelu_f(a1) * hv;
        #pragma unroll
        for (int m = 1; m < 64; m <<= 1) {
            c0 += __shfl_xor(c0, m);
            c1 += __shfl_xor(c1, m);
        }
        if (lane == 0) { s_red[wv][0] = c0; s_red[wv][1] = c1; }
    }
    __syncthreads();
    if (t == 0) {
        float u0 = s_red[0][0] + s_red[1][0] + s_red[2][0] + s_red[3][0] + hb2[0];
        float u1 = s_red[0][1] + s_red[1][1] + s_red[2][1] + s_red[3][1] + hb2[0];
        out[q0 + 0] = u0 * s_sig[0] + s_mu[0];
        out[q0 + 1] = u1 * s_sig[1] + s_mu[1];
    }
}

extern "C" void kernel_launch(void* const* d_in, const int* in_sizes, int n_in,
                              void* d_out, int out_size, void* d_ws, size_t ws_size,
                              hipStream_t stream)
{
    const float* xyt_q      = (const float*)d_in[0];
    const float* obs_coords = (const float*)d_in[1];
    const float* obs_vals   = (const float*)d_in[2];
    const int*   nb_idx     = (const int*)d_in[3];
    const float* log_gammas = (const float*)d_in[4];
    const float* w_in  = (const float*)d_in[5];
    const float* b_in  = (const float*)d_in[6];
    const float* ln1_g = (const float*)d_in[7];
    const float* ln1_b = (const float*)d_in[8];
    const float* w1    = (const float*)d_in[9];
    const float* b1    = (const float*)d_in[10];
    const float* w2    = (const float*)d_in[11];
    const float* b2    = (const float*)d_in[12];
    const float* hln_g = (const float*)d_in[13];
    const float* hln_b = (const float*)d_in[14];
    const float* hw1   = (const float*)d_in[15];
    const float* hb1   = (const float*)d_in[16];
    const float* hw2   = (const float*)d_in[17];
    const float* hb2   = (const float*)d_in[18];
    float* out = (float*)d_out;

    const int Q = in_sizes[0] / 3;   // 32768

    // ws: w1h 64K | w2h 64K | hw1h 128K
    _Float16* w1h  = (_Float16*)d_ws;
    _Float16* w2h  = w1h + 32768;
    _Float16* hw1h = (_Float16*)((char*)d_ws + 131072);

    prep_kernel<<<256, 256, 0, stream>>>(w1, w2, hw1, w1h, w2h, hw1h);

    ff_mfma_kernel<<<Q / QB, 256, 0, stream>>>(
        xyt_q, obs_coords, obs_vals, nb_idx, log_gammas,
        w_in, b_in, ln1_g, ln1_b,
        w1h, b1, w2h, b2,
        hln_g, hln_b, hw1h, hb1, hw2, hb2, out);
}

// Round 8
// 880.757 us; speedup vs baseline: 1.0546x; 1.0546x over previous
//
#include <hip/hip_runtime.h>
#include <math.h>

// Round 8: EXACT round-3 structure (proven 727 us, VALUBusy 78%) with the
// quantized chain in fp16 (validated round 7: accuracy margin 2.4x) instead
// of bf16. R4/R7's restructures (merged embed+LN, swapped GEMM2, head MFMA)
// are reverted: they cut VALU issue 567->411 us but added ~400 us of stall
// (lane-strided 512B-pitch weight loads touch ~4x the cache lines of R3's
// coalesced patterns -> TA/L1 pipe). R3's coalesced VALU head + unswapped
// GEMM2 stay. K-split (R5/R6) stays abandoned (unexplained 2.5x error).
#define KN 32
#define DD 128
#define FF 256
#define QB 2
#define MROWS 64
#define HP 136      // hln/h2 pitch (half): [64][136] = 17408 B
#define XP 264      // x pitch (half):      [64][264] = 33792 B (aliases hf)

typedef _Float16 f16x8 __attribute__((ext_vector_type(8)));
typedef float f32x4 __attribute__((ext_vector_type(4)));

__device__ __forceinline__ unsigned pk2h(float a, float b) {
    union { _Float16 h[2]; unsigned u; } c;
    c.h[0] = (_Float16)a; c.h[1] = (_Float16)b;
    return c.u;
}
// gelu via A&S 7.1.26 erf (|err|<=1.5e-7), pure VALU (validated R3/R7)
__device__ __forceinline__ float gelu_f(float x) {
    float z  = __builtin_fabsf(x) * 0.70710678118654752440f;
    float e  = __builtin_amdgcn_exp2f(z * z * -1.4426950408889634f);
    float t  = __builtin_amdgcn_rcpf(fmaf(0.3275911f, z, 1.0f));
    float p  = fmaf(1.061405429f, t, -1.453152027f);
    p = fmaf(p, t, 1.421413741f);
    p = fmaf(p, t, -0.284496736f);
    p = fmaf(p, t, 0.254829592f);
    p = p * t;
    float erfz = fmaf(-p, e, 1.0f);
    float erfs = (x < 0.0f) ? -erfz : erfz;
    float hx = 0.5f * x;
    return fmaf(hx, erfs, hx);
}

// Prep: w1 [256,128], w2 [128,256] -> fp16 natural; hw1 [256,256] ->
// transposed packed fp16 pairs: hw1p[c2*256+f] = (h(hw1[f][2c2]), h(hw1[f][2c2+1])).
__global__ void prep_kernel(const float* __restrict__ w1,
                            const float* __restrict__ w2,
                            const float* __restrict__ hw1,
                            _Float16* __restrict__ w1h,
                            _Float16* __restrict__ w2h,
                            unsigned* __restrict__ hw1p) {
    int i = blockIdx.x * 256 + threadIdx.x;   // 0..65535
    if (i < 32768) { w1h[i] = (_Float16)w1[i]; w2h[i] = (_Float16)w2[i]; }
    if (i < 65536) {
        int c2 = i >> 8, f = i & 255;
        hw1p[i] = pk2h(hw1[f * 256 + 2 * c2], hw1[f * 256 + 2 * c2 + 1]);
    }
}

__launch_bounds__(256, 3)
__global__ void ff_mfma_kernel(
    const float* __restrict__ xyt_q,
    const float* __restrict__ obs_coords,
    const float* __restrict__ obs_vals,
    const int*   __restrict__ nb_idx,
    const float* __restrict__ log_gammas,
    const float* __restrict__ w_in,   // [128,4]
    const float* __restrict__ b_in,
    const float* __restrict__ ln1_g,
    const float* __restrict__ ln1_b,
    const _Float16* __restrict__ w1h,  // [256,128] fp16
    const float* __restrict__ b1,
    const _Float16* __restrict__ w2h,  // [128,256] fp16
    const float* __restrict__ b2,
    const float* __restrict__ hln_g,
    const float* __restrict__ hln_b,
    const unsigned* __restrict__ hw1p, // [128,256] packed fp16 pairs (transposed)
    const float* __restrict__ hb1,
    const float* __restrict__ hw2,
    const float* __restrict__ hb2,
    float* __restrict__ out)
{
    __shared__ __align__(16) _Float16 s_hA[MROWS * HP];    // 17408 B: hln, then h2
    __shared__ __align__(16) unsigned char s_big[33792];   // hf fp32 [64][132] / x f16 [64][264]
    __shared__ __align__(16) float s_tokf[MROWS][4];
    __shared__ __align__(16) float s_pool[2 * DD * QB / 2]; // [2][256]
    __shared__ __align__(16) float s_pln[2 * DD * QB / 2];  // [2][256]
    __shared__ float s_mu[QB], s_sig[QB];
    __shared__ float s_red[4][QB];

    const int t    = threadIdx.x;
    const int lane = t & 63;
    const int wv   = t >> 6;
    const int m16  = lane & 15;
    const int quad = lane >> 4;
    const int q0   = blockIdx.x * QB;

    float*    hf  = (float*)s_big;        // [64][132] fp32 (phases 1-2)
    _Float16* s_x = (_Float16*)s_big;     // [64][264] fp16 (phases 3-4)

    // ---- Phase 0: gather, tokens, mu/sigma (ddof=1, clip 1e-3) ----
    if (t < MROWS) {
        int qi = t >> 5, j = t & 31;
        int q = q0 + qi;
        int idx = nb_idx[q * KN + j];
        float v = obs_vals[idx];
        float g0 = expf(log_gammas[0]), g1 = expf(log_gammas[1]), g2 = expf(log_gammas[2]);
        s_tokf[t][0] = (obs_coords[idx * 3 + 0] - xyt_q[q * 3 + 0]) * g0;
        s_tokf[t][1] = (obs_coords[idx * 3 + 1] - xyt_q[q * 3 + 1]) * g1;
        s_tokf[t][2] = (obs_coords[idx * 3 + 2] - xyt_q[q * 3 + 2]) * g2;
        float s = v, ss = v * v;
        #pragma unroll
        for (int m = 1; m < 32; m <<= 1) {
            s  += __shfl_xor(s, m);
            ss += __shfl_xor(ss, m);
        }
        float mu  = s * (1.0f / KN);
        float var = (ss - (float)KN * mu * mu) * (1.0f / (KN - 1));
        float sig = fmaxf(sqrtf(fmaxf(var, 0.0f)), 1e-3f);
        if (j == 0) { s_mu[qi] = mu; s_sig[qi] = sig; }
        s_tokf[t][3] = (v - mu) / sig;
    }
    __syncthreads();

    // ---- Phase 1: hf = gelu(tok @ w_in^T + b_in)  [64,128] fp32 ----
    #pragma unroll
    for (int i = 0; i < 32; i++) {
        int idx = t + 256 * i;         // 0..8191
        int tok = idx >> 7, d = idx & 127;
        float4 w  = ((const float4*)w_in)[d];
        float4 tk = *(const float4*)&s_tokf[tok][0];
        float a = fmaf(w.x, tk.x, fmaf(w.y, tk.y, fmaf(w.z, tk.z, fmaf(w.w, tk.w, b_in[d]))));
        hf[tok * 132 + d] = gelu_f(a);
    }
    __syncthreads();

    // ---- Phase 2: LN over 128 (fp32) -> fp16 s_hA; lane owns dims {2L,2L+1} ----
    {
        const float2 gg = *(const float2*)&ln1_g[2 * lane];
        const float2 cc = *(const float2*)&ln1_b[2 * lane];
        #pragma unroll
        for (int i = 0; i < 16; i++) {
            int tok = wv * 16 + i;
            float2 v01 = *(const float2*)&hf[tok * 132 + 2 * lane];
            float s = v01.x + v01.y, ss = v01.x * v01.x + v01.y * v01.y;
            #pragma unroll
            for (int m = 1; m < 64; m <<= 1) {
                s  += __shfl_xor(s, m);
                ss += __shfl_xor(ss, m);
            }
            float mean = s * (1.0f / DD);
            float var  = ss * (1.0f / DD) - mean * mean;
            float rstd = rsqrtf(fmaxf(var, 0.0f) + 1e-5f);
            float y0 = fmaf((v01.x - mean) * rstd, gg.x, cc.x);
            float y1 = fmaf((v01.y - mean) * rstd, gg.y, cc.y);
            *(unsigned*)&s_hA[tok * HP + 2 * lane] = pk2h(y0, y1);
        }
    }
    __syncthreads();

    // ---- Phase 3: MFMA GEMM1  x = gelu(hln @ w1^T + b1); wave strip F in [wv*64,+64) ----
    {
        f16x8 B[4][4];
        #pragma unroll
        for (int ct = 0; ct < 4; ct++)
            #pragma unroll
            for (int kk = 0; kk < 4; kk++)
                B[ct][kk] = *(const f16x8*)&w1h[(wv * 64 + ct * 16 + m16) * 128 + kk * 32 + quad * 8];
        #pragma unroll
        for (int rt = 0; rt < 4; rt++) {
            f16x8 A[4];
            #pragma unroll
            for (int kk = 0; kk < 4; kk++)
                A[kk] = *(const f16x8*)&s_hA[(rt * 16 + m16) * HP + kk * 32 + quad * 8];
            #pragma unroll
            for (int ct = 0; ct < 4; ct++) {
                f32x4 acc = {0.f, 0.f, 0.f, 0.f};
                #pragma unroll
                for (int kk = 0; kk < 4; kk++)
                    acc = __builtin_amdgcn_mfma_f32_16x16x32_f16(A[kk], B[ct][kk], acc, 0, 0, 0);
                int col = wv * 64 + ct * 16 + m16;
                float bb = b1[col];
                int r0 = rt * 16 + quad * 4;
                s_x[(r0 + 0) * XP + col] = (_Float16)gelu_f(acc[0] + bb);
                s_x[(r0 + 1) * XP + col] = (_Float16)gelu_f(acc[1] + bb);
                s_x[(r0 + 2) * XP + col] = (_Float16)gelu_f(acc[2] + bb);
                s_x[(r0 + 3) * XP + col] = (_Float16)gelu_f(acc[3] + bb);
            }
        }
    }
    __syncthreads();

    // ---- Phase 4: MFMA GEMM2  h2 = gelu(x @ w2^T + b2); wave strip D in [wv*32,+32) ----
    {
        f16x8 B2[2][8];
        #pragma unroll
        for (int ct = 0; ct < 2; ct++)
            #pragma unroll
            for (int kk = 0; kk < 8; kk++)
                B2[ct][kk] = *(const f16x8*)&w2h[(wv * 32 + ct * 16 + m16) * 256 + kk * 32 + quad * 8];
        #pragma unroll
        for (int rt = 0; rt < 4; rt++) {
            f16x8 A[8];
            #pragma unroll
            for (int kk = 0; kk < 8; kk++)
                A[kk] = *(const f16x8*)&s_x[(rt * 16 + m16) * XP + kk * 32 + quad * 8];
            #pragma unroll
            for (int ct = 0; ct < 2; ct++) {
                f32x4 acc = {0.f, 0.f, 0.f, 0.f};
                #pragma unroll
                for (int kk = 0; kk < 8; kk++)
                    acc = __builtin_amdgcn_mfma_f32_16x16x32_f16(A[kk], B2[ct][kk], acc, 0, 0, 0);
                int col = wv * 32 + ct * 16 + m16;
                float bb = b2[col];
                if (rt == 0 && ct == 0) __syncthreads();   // defensive, as in R3 (proven config)
                int r0 = rt * 16 + quad * 4;
                s_hA[(r0 + 0) * HP + col] = (_Float16)gelu_f(acc[0] + bb);
                s_hA[(r0 + 1) * HP + col] = (_Float16)gelu_f(acc[1] + bb);
                s_hA[(r0 + 2) * HP + col] = (_Float16)gelu_f(acc[2] + bb);
                s_hA[(r0 + 3) * HP + col] = (_Float16)gelu_f(acc[3] + bb);
            }
        }
    }
    __syncthreads();

    // ---- Phase 5: pool mean/max over K=32 per query ----
    if (t < DD) {
        float sm = 0.f, mx = -INFINITY;
        #pragma unroll
        for (int k = 0; k < KN; k++) {
            float v = (float)s_hA[k * HP + t];
            sm += v; mx = fmaxf(mx, v);
        }
        s_pool[t]       = sm * (1.0f / KN);
        s_pool[DD + t]  = mx;
        float sm2 = 0.f, mx2 = -INFINITY;
        #pragma unroll
        for (int k = KN; k < 2 * KN; k++) {
            float v = (float)s_hA[k * HP + t];
            sm2 += v; mx2 = fmaxf(mx2, v);
        }
        s_pool[256 + t]      = sm2 * (1.0f / KN);
        s_pool[256 + DD + t] = mx2;
    }
    __syncthreads();

    // ---- Phase 6: head LN over 256 (one wave per query) -> s_pln fp32 ----
    if (t < 128) {
        int qi = t >> 6, l = t & 63;
        float v0 = s_pool[qi * 256 + l],       v1 = s_pool[qi * 256 + l + 64];
        float v2 = s_pool[qi * 256 + l + 128], v3 = s_pool[qi * 256 + l + 192];
        float s = v0 + v1 + v2 + v3;
        float ss = v0 * v0 + v1 * v1 + v2 * v2 + v3 * v3;
        #pragma unroll
        for (int m = 1; m < 64; m <<= 1) {
            s  += __shfl_xor(s, m);
            ss += __shfl_xor(ss, m);
        }
        float mean = s * (1.0f / (2 * DD));
        float var  = ss * (1.0f / (2 * DD)) - mean * mean;
        float rstd = rsqrtf(fmaxf(var, 0.0f) + 1e-5f);
        s_pln[qi * 256 + l]       = (v0 - mean) * rstd * hln_g[l]       + hln_b[l];
        s_pln[qi * 256 + l + 64]  = (v1 - mean) * rstd * hln_g[l + 64]  + hln_b[l + 64];
        s_pln[qi * 256 + l + 128] = (v2 - mean) * rstd * hln_g[l + 128] + hln_b[l + 128];
        s_pln[qi * 256 + l + 192] = (v3 - mean) * rstd * hln_g[l + 192] + hln_b[l + 192];
    }
    __syncthreads();

    // ---- Phase 7: head MLP, thread t = hidden unit f, both queries (coalesced) ----
    {
        float a0 = hb1[t], a1 = a0;
        #pragma unroll 8
        for (int c2 = 0; c2 < 128; c2++) {
            union { unsigned u; _Float16 h[2]; } w;
            w.u = hw1p[c2 * 256 + t];                 // coalesced 4B/lane
            float w0 = (float)w.h[0], w1 = (float)w.h[1];
            float p00 = s_pln[2 * c2], p01 = s_pln[2 * c2 + 1];
            float p10 = s_pln[256 + 2 * c2], p11 = s_pln[256 + 2 * c2 + 1];
            a0 = fmaf(w0, p00, fmaf(w1, p01, a0));
            a1 = fmaf(w0, p10, fmaf(w1, p11, a1));
        }
        float hv = hw2[t];
        float c0 = gelu_f(a0) * hv, c1 = gelu_f(a1) * hv;
        #pragma unroll
        for (int m = 1; m < 64; m <<= 1) {
            c0 += __shfl_xor(c0, m);
            c1 += __shfl_xor(c1, m);
        }
        if (lane == 0) { s_red[wv][0] = c0; s_red[wv][1] = c1; }
    }
    __syncthreads();
    if (t == 0) {
        float u0 = s_red[0][0] + s_red[1][0] + s_red[2][0] + s_red[3][0] + hb2[0];
        float u1 = s_red[0][1] + s_red[1][1] + s_red[2][1] + s_red[3][1] + hb2[0];
        out[q0 + 0] = u0 * s_sig[0] + s_mu[0];
        out[q0 + 1] = u1 * s_sig[1] + s_mu[1];
    }
}

extern "C" void kernel_launch(void* const* d_in, const int* in_sizes, int n_in,
                              void* d_out, int out_size, void* d_ws, size_t ws_size,
                              hipStream_t stream)
{
    const float* xyt_q      = (const float*)d_in[0];
    const float* obs_coords = (const float*)d_in[1];
    const float* obs_vals   = (const float*)d_in[2];
    const int*   nb_idx     = (const int*)d_in[3];
    const float* log_gammas = (const float*)d_in[4];
    const float* w_in  = (const float*)d_in[5];
    const float* b_in  = (const float*)d_in[6];
    const float* ln1_g = (const float*)d_in[7];
    const float* ln1_b = (const float*)d_in[8];
    const float* w1    = (const float*)d_in[9];
    const float* b1    = (const float*)d_in[10];
    const float* w2    = (const float*)d_in[11];
    const float* b2    = (const float*)d_in[12];
    const float* hln_g = (const float*)d_in[13];
    const float* hln_b = (const float*)d_in[14];
    const float* hw1   = (const float*)d_in[15];
    const float* hb1   = (const float*)d_in[16];
    const float* hw2   = (const float*)d_in[17];
    const float* hb2   = (const float*)d_in[18];
    float* out = (float*)d_out;

    const int Q = in_sizes[0] / 3;   // 32768

    // ws: w1h 64K | w2h 64K | hw1p 256K
    _Float16* w1h  = (_Float16*)d_ws;
    _Float16* w2h  = w1h + 32768;
    unsigned* hw1p = (unsigned*)((char*)d_ws + 131072);

    prep_kernel<<<256, 256, 0, stream>>>(w1, w2, hw1, w1h, w2h, hw1p);

    ff_mfma_kernel<<<Q / QB, 256, 0, stream>>>(
        xyt_q, obs_coords, obs_vals, nb_idx, log_gammas,
        w_in, b_in, ln1_g, ln1_b,
        w1h, b1, w2h, b2,
        hln_g, hln_b, hw1p, hb1, hw2, hb2, out);
}